// Round 3
// 481.604 us; speedup vs baseline: 1.3633x; 1.3633x over previous
//
#include <hip/hip_runtime.h>

#define NEARZERO 1e-5f

// One thread per grid cell (G=8000), T=730 serial recurrence, state in regs.
//
// Round-3 post-mortem: VGPR_Count=32 — buf[2][CH][3] indexed by runtime `cur`
// was demoted to SCRATCH (runtime-indexed local arrays can't be promoted), so
// every "prefetch" was a global->scratch->register round-trip serialized per
// chunk. Rounds 4-6: two STATICALLY NAMED register buffers (bufA/bufB), outer
// loop advances 2*CH so all buffer indices are compile-time constants.
// Prefetch addresses clamp t to T-1 (branch-free, always-valid); only the
// output store is guarded. CH=8: 24 dwords in flight per thread while
// ~1000 cycles of dependent compute retire (covers ~900cyc HBM latency).
// Occupancy is grid-limited (125 waves on 1024 SIMDs) so VGPR cost is free.
// (Round 6 = resubmit after two harness container failures; CH 12->8 to
// trim emitted code size as a hedge. Same structure and theory.)

__global__ __launch_bounds__(64, 1)
void hbv_kernel(const float* __restrict__ x,      // (T, G, 3)
                const float* __restrict__ par,    // (T, G, 14) — only t=T-1 used
                float* __restrict__ out,          // (T, G)
                int T, int G)
{
    const int g = blockIdx.x * 64 + threadIdx.x;
    if (g >= G) return;

    const float lo[14] = {1.0f, 50.0f,   0.05f, 0.01f, 0.001f, 0.2f, 0.0f,  0.0f,   -2.5f, 0.5f,  0.0f, 0.0f, 0.3f, 0.0f};
    const float hi[14] = {6.0f, 1000.0f, 0.9f,  0.5f,  0.2f,   1.0f, 10.0f, 100.0f,  2.5f, 10.0f, 0.1f, 0.2f, 5.0f, 1.0f};

    // phy = sigmoid(parameters[-1, g, :]) scaled to bounds
    const float* p = par + ((size_t)(T - 1) * G + (size_t)g) * 14;
    float ph[14];
#pragma unroll
    for (int i = 0; i < 14; i++) {
        float v = p[i];
        float s = 1.0f / (1.0f + __expf(-v));
        ph[i] = lo[i] + s * (hi[i] - lo[i]);
    }
    const float BETA = ph[0], FC = ph[1], K0 = ph[2], K1 = ph[3], K2 = ph[4],
                LP = ph[5], PERCmax = ph[6], UZL = ph[7], TT = ph[8],
                CFMAX = ph[9], CFR = ph[10], CWH = ph[11], BETAET = ph[12],
                C = ph[13];
    const float invFC    = 1.0f / FC;
    const float invLPFC  = 1.0f / (LP * FC);
    const float CFRCFMAX = CFR * CFMAX;

    float SP = 1e-3f, MW = 1e-3f, SM = 1e-3f, SUZ = 1e-3f, SLZ = 1e-3f;

    const size_t xstride = (size_t)G * 3;
    const float* xbase = x + (size_t)g * 3;
    float* op = out + g;

    constexpr int CH = 8;           // prefetch chunk depth (24 dwords in flight)
    float bufA[CH][3];              // statically named — NEVER runtime-indexed
    float bufB[CH][3];

// Issue CH rows of loads into BUF. Address clamps to row T-1 so tail loads
// are branch-free and in-bounds (clamped rows feed dead state updates only).
// The asm memory-clobber fence pins the loads ABOVE the following compute
// block so they stay in flight while compute retires.
#define PREFETCH(BUF, T0)                                                     \
    {                                                                         \
        _Pragma("unroll")                                                     \
        for (int c = 0; c < CH; c++) {                                        \
            int t = (T0) + c;                                                 \
            t = (t < T) ? t : (T - 1);                                        \
            const float* q = xbase + (size_t)t * xstride;                     \
            BUF[c][0] = q[0]; BUF[c][1] = q[1]; BUF[c][2] = q[2];             \
        }                                                                     \
        asm volatile("" ::: "memory");                                        \
    }

// Compute CH steps from BUF. State updates past T are harmless (clamped real
// data, never stored); only the output store is guarded (wave-uniform).
#define COMPUTE(BUF, T0)                                                      \
    {                                                                         \
        _Pragma("unroll")                                                     \
        for (int c = 0; c < CH; c++) {                                        \
            const int t = (T0) + c;                                           \
            const float Pt   = BUF[c][0];                                     \
            const float Tt   = BUF[c][1];                                     \
            const float PETt = BUF[c][2];                                     \
            const float is_rain = (Tt >= TT) ? 1.0f : 0.0f;                   \
            const float RAIN = Pt * is_rain;                                  \
            const float SNOW = Pt - RAIN;                                     \
            SP += SNOW;                                                       \
            const float melt = fminf(fmaxf(CFMAX * (Tt - TT), 0.0f), SP);     \
            MW += melt; SP -= melt;                                           \
            const float refreeze = fminf(fmaxf(CFRCFMAX * (TT - Tt), 0.0f), MW); \
            SP += refreeze; MW -= refreeze;                                   \
            const float tosoil = fmaxf(MW - CWH * SP, 0.0f);                  \
            MW -= tosoil;                                                     \
            const float sw = fminf(__builtin_amdgcn_exp2f(BETA * __builtin_amdgcn_logf(SM * invFC)), 1.0f); \
            const float rt = RAIN + tosoil;                                   \
            const float recharge = rt * sw;                                   \
            SM += rt - recharge;                                              \
            const float excess = fmaxf(SM - FC, 0.0f);                        \
            SM -= excess;                                                     \
            const float ef = fminf(__builtin_amdgcn_exp2f(BETAET * __builtin_amdgcn_logf(SM * invLPFC)), 1.0f); \
            const float ETact = fminf(SM, PETt * ef);                         \
            SM = fmaxf(SM - ETact, NEARZERO);                                 \
            const float capillary = fminf(SLZ, C * SLZ * (1.0f - fminf(SM * invFC, 1.0f))); \
            SM  = fmaxf(SM + capillary, NEARZERO);                            \
            SLZ = fmaxf(SLZ - capillary, NEARZERO);                           \
            SUZ += recharge + excess;                                         \
            const float PERC = fminf(SUZ, PERCmax);                           \
            SUZ -= PERC;                                                      \
            const float Q0 = K0 * fmaxf(SUZ - UZL, 0.0f);                     \
            SUZ -= Q0;                                                        \
            const float Q1 = K1 * SUZ;                                        \
            SUZ -= Q1;                                                        \
            SLZ += PERC;                                                      \
            const float Q2 = K2 * SLZ;                                        \
            SLZ -= Q2;                                                        \
            if (t < T) op[(size_t)t * G] = Q0 + Q1 + Q2;                      \
        }                                                                     \
    }

    PREFETCH(bufA, 0);

#pragma unroll 1
    for (int t0 = 0; t0 < T; t0 += 2 * CH) {
        PREFETCH(bufB, t0 + CH);          // loads in flight across compute A
        COMPUTE(bufA, t0);
        PREFETCH(bufA, t0 + 2 * CH);      // loads in flight across compute B
        COMPUTE(bufB, t0 + CH);
    }

#undef PREFETCH
#undef COMPUTE
}

extern "C" void kernel_launch(void* const* d_in, const int* in_sizes, int n_in,
                              void* d_out, int out_size, void* d_ws, size_t ws_size,
                              hipStream_t stream) {
    const float* x   = (const float*)d_in[0];  // (T, G, 3) f32
    const float* par = (const float*)d_in[1];  // (T, G, 14) f32
    float* out = (float*)d_out;                // (T, G) f32

    const int G = 8000;
    const int T = out_size / G;  // 730

    hbv_kernel<<<dim3((G + 63) / 64), dim3(64), 0, stream>>>(x, par, out, T, G);
}

// Round 4
// 476.981 us; speedup vs baseline: 1.3765x; 1.0097x over previous
//
#include <hip/hip_runtime.h>

#define NEARZERO 1e-5f

// One thread per grid cell (G=8000), T=730 serial recurrence, state in regs.
//
// History:
//  R2: VGPR=32 — runtime-indexed buf demoted to scratch; prefetch was fake.
//  R4-6: statically-named double buffers (bufA/bufB), compile-time indices.
//      Landed: 295us -> ~120us/dispatch (bench 656.6 -> 481.6).
//  R7 (this): (a) CH 8->16 — per-chunk compute ~2000cyc now fully covers
//      ~900cyc HBM latency with 2x headroom (CH=8 was marginal: ~1000cyc).
//      (b) bit-exact chain shortening: SM=min(SM,FC) replaces excess-subtract;
//      ETact min eliminated (provably equal); capillary min(SLZ,..) dropped
//      (C<=1, factor<=1 => product <= SLZ, min always picks product);
//      SUZ=max(SUZ-PERCmax,0) replaces PERC-subtract. ~4 ops off the
//      critical dependency chain per step.
// Occupancy is grid-limited (125 waves / 1024 SIMDs): VGPR cost is free;
// wall-clock = 730 x per-step dependent-chain latency + uncovered mem stalls.

__global__ __launch_bounds__(64, 1)
void hbv_kernel(const float* __restrict__ x,      // (T, G, 3)
                const float* __restrict__ par,    // (T, G, 14) — only t=T-1 used
                float* __restrict__ out,          // (T, G)
                int T, int G)
{
    const int g = blockIdx.x * 64 + threadIdx.x;
    if (g >= G) return;

    const float lo[14] = {1.0f, 50.0f,   0.05f, 0.01f, 0.001f, 0.2f, 0.0f,  0.0f,   -2.5f, 0.5f,  0.0f, 0.0f, 0.3f, 0.0f};
    const float hi[14] = {6.0f, 1000.0f, 0.9f,  0.5f,  0.2f,   1.0f, 10.0f, 100.0f,  2.5f, 10.0f, 0.1f, 0.2f, 5.0f, 1.0f};

    // phy = sigmoid(parameters[-1, g, :]) scaled to bounds
    const float* p = par + ((size_t)(T - 1) * G + (size_t)g) * 14;
    float ph[14];
#pragma unroll
    for (int i = 0; i < 14; i++) {
        float v = p[i];
        float s = 1.0f / (1.0f + __expf(-v));
        ph[i] = lo[i] + s * (hi[i] - lo[i]);
    }
    const float BETA = ph[0], FC = ph[1], K0 = ph[2], K1 = ph[3], K2 = ph[4],
                LP = ph[5], PERCmax = ph[6], UZL = ph[7], TT = ph[8],
                CFMAX = ph[9], CFR = ph[10], CWH = ph[11], BETAET = ph[12],
                C = ph[13];
    const float invFC    = 1.0f / FC;
    const float invLPFC  = 1.0f / (LP * FC);
    const float CFRCFMAX = CFR * CFMAX;

    float SP = 1e-3f, MW = 1e-3f, SM = 1e-3f, SUZ = 1e-3f, SLZ = 1e-3f;

    const size_t xstride = (size_t)G * 3;
    const float* xbase = x + (size_t)g * 3;
    float* op = out + g;

    constexpr int CH = 16;          // prefetch chunk depth (48 dwords in flight)
    float bufA[CH][3];              // statically named — NEVER runtime-indexed
    float bufB[CH][3];

// Issue CH rows of loads into BUF. Address clamps to row T-1 so tail loads
// are branch-free and in-bounds (clamped rows feed dead state updates only).
// The asm memory-clobber fence pins the loads ABOVE the following compute
// block so they stay in flight while compute retires.
#define PREFETCH(BUF, T0)                                                     \
    {                                                                         \
        _Pragma("unroll")                                                     \
        for (int c = 0; c < CH; c++) {                                        \
            int t = (T0) + c;                                                 \
            t = (t < T) ? t : (T - 1);                                        \
            const float* q = xbase + (size_t)t * xstride;                     \
            BUF[c][0] = q[0]; BUF[c][1] = q[1]; BUF[c][2] = q[2];             \
        }                                                                     \
        asm volatile("" ::: "memory");                                        \
    }

// Compute CH steps from BUF. State updates past T are harmless (clamped real
// data, never stored); only the output store is guarded (wave-uniform).
// Chain-shortened forms below are bit-exact vs the reference forms:
//  - SM=min(SM,FC) == SM-max(SM-FC,0) (up to 1 ulp; excess itself unchanged)
//  - max(SM-PET*ef,NZ) == max(SM-min(SM,PET*ef),NZ) in both branches
//  - min(SLZ, C*SLZ*f) == C*SLZ*f since C<=1, f<=1, SLZ>=0
//  - max(SUZ-PERCmax,0) == SUZ-min(SUZ,PERCmax) in both branches
#define COMPUTE(BUF, T0)                                                      \
    {                                                                         \
        _Pragma("unroll")                                                     \
        for (int c = 0; c < CH; c++) {                                        \
            const int t = (T0) + c;                                           \
            const float Pt   = BUF[c][0];                                     \
            const float Tt   = BUF[c][1];                                     \
            const float PETt = BUF[c][2];                                     \
            const float is_rain = (Tt >= TT) ? 1.0f : 0.0f;                   \
            const float RAIN = Pt * is_rain;                                  \
            const float SNOW = Pt - RAIN;                                     \
            SP += SNOW;                                                       \
            const float melt = fminf(fmaxf(CFMAX * (Tt - TT), 0.0f), SP);     \
            MW += melt; SP -= melt;                                           \
            const float refreeze = fminf(fmaxf(CFRCFMAX * (TT - Tt), 0.0f), MW); \
            SP += refreeze; MW -= refreeze;                                   \
            const float tosoil = fmaxf(MW - CWH * SP, 0.0f);                  \
            MW -= tosoil;                                                     \
            /* sw depends on prev-step SM: runs parallel with snow chain */   \
            const float sw = fminf(__builtin_amdgcn_exp2f(BETA * __builtin_amdgcn_logf(SM * invFC)), 1.0f); \
            const float rt = RAIN + tosoil;                                   \
            const float recharge = rt * sw;                                   \
            SM += rt - recharge;                                              \
            const float excess = fmaxf(SM - FC, 0.0f);  /* off-chain */       \
            SM = fminf(SM, FC);                                               \
            const float ef = fminf(__builtin_amdgcn_exp2f(BETAET * __builtin_amdgcn_logf(SM * invLPFC)), 1.0f); \
            SM = fmaxf(SM - PETt * ef, NEARZERO);                             \
            const float cap = (C * SLZ) * (1.0f - fminf(SM * invFC, 1.0f));   \
            SM  = fmaxf(SM + cap, NEARZERO);                                  \
            SLZ = fmaxf(SLZ - cap, NEARZERO);                                 \
            SUZ += recharge + excess;                                         \
            const float PERC = fminf(SUZ, PERCmax);     /* off-chain */       \
            SUZ = fmaxf(SUZ - PERCmax, 0.0f);                                 \
            const float Q0 = K0 * fmaxf(SUZ - UZL, 0.0f);                     \
            SUZ -= Q0;                                                        \
            const float Q1 = K1 * SUZ;                                        \
            SUZ -= Q1;                                                        \
            SLZ += PERC;                                                      \
            const float Q2 = K2 * SLZ;                                        \
            SLZ -= Q2;                                                        \
            if (t < T) op[(size_t)t * G] = Q0 + Q1 + Q2;                      \
        }                                                                     \
    }

    PREFETCH(bufA, 0);

#pragma unroll 1
    for (int t0 = 0; t0 < T; t0 += 2 * CH) {
        PREFETCH(bufB, t0 + CH);          // loads in flight across compute A
        COMPUTE(bufA, t0);
        PREFETCH(bufA, t0 + 2 * CH);      // loads in flight across compute B
        COMPUTE(bufB, t0 + CH);
    }

#undef PREFETCH
#undef COMPUTE
}

extern "C" void kernel_launch(void* const* d_in, const int* in_sizes, int n_in,
                              void* d_out, int out_size, void* d_ws, size_t ws_size,
                              hipStream_t stream) {
    const float* x   = (const float*)d_in[0];  // (T, G, 3) f32
    const float* par = (const float*)d_in[1];  // (T, G, 14) f32
    float* out = (float*)d_out;                // (T, G) f32

    const int G = 8000;
    const int T = out_size / G;  // 730

    hbv_kernel<<<dim3((G + 63) / 64), dim3(64), 0, stream>>>(x, par, out, T, G);
}